// Round 4
// baseline (887.521 us; speedup 1.0000x reference)
//
#include <hip/hip_runtime.h>

// BasicNCA: 16 sequential steps of (11x11 SAME conv -> per-pixel MLP 1->10->10->1
// -> residual -> clip[0,1]) on (16,1,256,256) fp32.
// out = 17 slabs (x, then 16 steps).
//
// R4: single plain-launch kernel + hand-rolled grid barrier (graph-capture safe;
// R3's hipLaunchCooperativeKernel never executed).
//  - 512 blocks x 512 threads, launch_bounds(512,4) => VGPR<=128 => 2 blocks/CU
//    => all 512 blocks resident at dispatch => spin barrier cannot deadlock
//  - per-phase arrival counters in d_ws (memset-0 node each call, no reuse hazard)
//  - release: __threadfence() (agent scope, L2 writeback => cross-XCD safe)
//    acquire: __hip_atomic_load(..., ACQUIRE, AGENT) spin by thread 0 only
//  - body = R1/R3 proven arithmetic: 64x32 tile, 4 px/thread, float4 LDS staging

#define HH 256
#define WW 256
#define BB 16
#define TH 32
#define TW 64
#define SH 42          // TH + 10 halo rows
#define SW 80          // staged cols: gx0-8 .. gx0+71 (16B-aligned superset)
#define SLAB (BB * HH * WW)
#define NSTEPS 16
#define NBLK 512

__global__ __launch_bounds__(512, 4) void nca_fused(
    const float* __restrict__ x, float* __restrict__ out,
    unsigned* __restrict__ bar,
    const float* __restrict__ Kk,
    const float* __restrict__ w1, const float* __restrict__ b1,
    const float* __restrict__ w2, const float* __restrict__ b2,
    const float* __restrict__ w3, const float* __restrict__ b3) {
    __shared__ __align__(16) float s[SH * SW];

    const int tid = threadIdx.x;
    const int b   = blockIdx.z;
    const int gy0 = blockIdx.y * TH;
    const int gx0 = blockIdx.x * TW;
    const int tx  = tid & 15, ty = tid >> 4;   // 16 x 32 threads
    const int x0  = tx * 4;                    // 4 output px per thread

    for (int k = 0; k < NSTEPS; ++k) {
        const float* img = ((k == 0) ? x : out + (size_t)k * SLAB) + b * HH * WW;

        // ---- stage 42 rows x 20 float4-cols; each float4 fully in or fully out ----
#pragma unroll
        for (int it = 0; it < 2; ++it) {
            int t = tid + it * 512;
            if (t < SH * (SW / 4)) {
                int r = t / (SW / 4), c = t - r * (SW / 4);
                int gy = gy0 - 5 + r, gx = gx0 - 8 + c * 4;
                float4 v = make_float4(0.f, 0.f, 0.f, 0.f);
                if ((unsigned)gy < HH && (unsigned)gx < WW)
                    v = *(const float4*)(img + gy * WW + gx);
                *(float4*)(s + r * SW + c * 4) = v;
            }
        }
        __syncthreads();

        if (k == 0) {  // slab 0 = x, written from the staged tile
            int r = tid >> 4, c4 = tid & 15;
            float4 v = *(const float4*)(s + (r + 5) * SW + c4 * 4 + 8);
            *(float4*)(out + (size_t)b * HH * WW + (gy0 + r) * WW + gx0 + c4 * 4) = v;
        }

        // ---- 11x11 conv: out px (x0+p) needs staged cols x0+p+3 .. x0+p+13 ----
        float acc[4] = {0.f, 0.f, 0.f, 0.f};
        float xc[4];
#pragma unroll
        for (int ky = 0; ky < 11; ++ky) {
            const float* row = &s[(ty + ky) * SW + x0];
            float win[20];
            *(float4*)(win + 0)  = *(const float4*)(row + 0);
            *(float4*)(win + 4)  = *(const float4*)(row + 4);
            *(float4*)(win + 8)  = *(const float4*)(row + 8);
            *(float4*)(win + 12) = *(const float4*)(row + 12);
            *(float4*)(win + 16) = *(const float4*)(row + 16);
            if (ky == 5) {
#pragma unroll
                for (int p = 0; p < 4; ++p) xc[p] = win[p + 8];  // center col
            }
            const float* krow = Kk + ky * 11;
            float kr[11];
#pragma unroll
            for (int j = 0; j < 11; ++j) kr[j] = krow[j];  // uniform -> s_load
#pragma unroll
            for (int kx = 0; kx < 11; ++kx) {
#pragma unroll
                for (int p = 0; p < 4; ++p)
                    acc[p] = fmaf(win[kx + p + 3], kr[kx], acc[p]);
            }
        }

        // ---- MLP 1->10->10->1 (interchanged: each weight loaded once / 4 px) ----
        const float b3v = b3[0];
        float h1[4][10];
#pragma unroll
        for (int i = 0; i < 10; ++i) {
            float w1i = w1[i], b1i = b1[i];
#pragma unroll
            for (int p = 0; p < 4; ++p)
                h1[p][i] = fmaxf(fmaf(acc[p], w1i, b1i), 0.f);
        }
        float yv[4] = {b3v, b3v, b3v, b3v};
#pragma unroll
        for (int o = 0; o < 10; ++o) {
            float b2o = b2[o];
            float a[4] = {b2o, b2o, b2o, b2o};
#pragma unroll
            for (int i = 0; i < 10; ++i) {
                float w = w2[o * 10 + i];
#pragma unroll
                for (int p = 0; p < 4; ++p)
                    a[p] = fmaf(h1[p][i], w, a[p]);
            }
            float w3o = w3[o];
#pragma unroll
            for (int p = 0; p < 4; ++p)
                yv[p] = fmaf(fmaxf(a[p], 0.f), w3o, yv[p]);
        }

        float res[4];
#pragma unroll
        for (int p = 0; p < 4; ++p)
            res[p] = fminf(fmaxf(xc[p] + yv[p], 0.f), 1.f);

        float* drow = out + (size_t)(k + 1) * SLAB + b * HH * WW +
                      (gy0 + ty) * WW + gx0 + x0;
        *(float4*)drow = make_float4(res[0], res[1], res[2], res[3]);

        // ---- grid barrier (skip after last step) ----
        if (k < NSTEPS - 1) {
            __syncthreads();  // block writes drained (compiler emits vmcnt(0))
            if (tid == 0) {
                __threadfence();              // agent-scope release: L2 writeback
                atomicAdd(&bar[k], 1u);       // device-scope arrival, phase k
                while (__hip_atomic_load(&bar[k], __ATOMIC_ACQUIRE,
                                         __HIP_MEMORY_SCOPE_AGENT) < NBLK) {
                    __builtin_amdgcn_s_sleep(2);
                }
            }
            __syncthreads();  // fan-out: rest of block ordered after acquire
        }
    }
}

extern "C" void kernel_launch(void* const* d_in, const int* in_sizes, int n_in,
                              void* d_out, int out_size, void* d_ws, size_t ws_size,
                              hipStream_t stream) {
    const float* x  = (const float*)d_in[0];
    const float* Kk = (const float*)d_in[1];
    const float* w1 = (const float*)d_in[2];
    const float* b1 = (const float*)d_in[3];
    const float* w2 = (const float*)d_in[4];
    const float* b2 = (const float*)d_in[5];
    const float* w3 = (const float*)d_in[6];
    const float* b3 = (const float*)d_in[7];
    float* out = (float*)d_out;
    unsigned* bar = (unsigned*)d_ws;

    // zero the 15 phase counters (d_ws is re-poisoned 0xAA before every call)
    hipMemsetAsync(bar, 0, (NSTEPS - 1) * sizeof(unsigned), stream);

    dim3 grid(WW / TW, HH / TH, BB);  // 4 x 8 x 16 = 512 blocks, 2/CU resident
    nca_fused<<<grid, 512, 0, stream>>>(x, out, bar, Kk, w1, b1, w2, b2, w3, b3);
}

// Round 6
// 389.802 us; speedup vs baseline: 2.2768x; 2.2768x over previous
//
#include <hip/hip_runtime.h>

// BasicNCA: 16 steps of (11x11 SAME conv -> MLP 1->10->10->1 -> residual -> clip)
// on (16,1,256,256) fp32. out = 17 slabs. Step k: slab k -> slab k+1.
//
// R6 = R5 with the fast-path SIGN BUG fixed (f(v) = v*A for v>=0, (-v)*B for v<0;
// R5 wrongly used v*B for v<0 -> absmax exactly 1.0), plus occupancy repair:
//  - 256-thread blocks, 4x2 px/thread -> 512 blocks x 4 waves = 2 waves/SIMD
//    (R5's 128-thr blocks gave 1 wave/SIMD: no latency hiding)
//  - LDS stride 96 words + XOR block swizzle sw=(row>>1)&3 (wave rows differ by 2)
//  - K hoisted in two batches (ky 0..4 / 5..10): no in-loop lgkmcnt drains
//  - zero-bias flag stored as float (no int-punning)
//  - full-MLP fallback kept for nonzero biases (correct for any input)

#define HH 256
#define WW 256
#define BB 16
#define TW 64
#define TH 32
#define SROWS 42       // TH + 10 halo rows
#define NBLKX 21       // staged float4-blocks per row (cols gx0-8 .. gx0+75)
#define SSTR 96        // LDS row stride in words (24 blocks; swizzle space)
#define SLAB (BB * HH * WW)
#define NSTEPS 16

__global__ __launch_bounds__(256) void nca_copy_x(const float* __restrict__ x,
                                                  float* __restrict__ out) {
    int i = (blockIdx.x * 256 + threadIdx.x) * 4;
    *(float4*)(out + i) = *(const float4*)(x + i);
}

__device__ float mlp_full(float v, const float* w1, const float* b1,
                          const float* w2, const float* b2,
                          const float* w3, const float* b3) {
    float h1[10];
#pragma unroll
    for (int i = 0; i < 10; ++i) h1[i] = fmaxf(fmaf(v, w1[i], b1[i]), 0.f);
    float y = b3[0];
#pragma unroll
    for (int o = 0; o < 10; ++o) {
        float a = b2[o];
#pragma unroll
        for (int i = 0; i < 10; ++i) a = fmaf(h1[i], w2[o * 10 + i], a);
        y = fmaf(fmaxf(a, 0.f), w3[o], y);
    }
    return y;
}

__global__ void nca_coef(const float* __restrict__ w1, const float* __restrict__ b1,
                         const float* __restrict__ w2, const float* __restrict__ b2,
                         const float* __restrict__ w3, const float* __restrict__ b3,
                         float* __restrict__ cf) {
    if (threadIdx.x == 0) {
        bool zero = (b3[0] == 0.f);
        for (int i = 0; i < 10; ++i) zero = zero && (b1[i] == 0.f) && (b2[i] == 0.f);
        cf[0] = mlp_full(1.f, w1, b1, w2, b2, w3, b3);   // A = f(+1)
        cf[1] = mlp_full(-1.f, w1, b1, w2, b2, w3, b3);  // B = f(-1)
        cf[2] = zero ? 1.f : 0.f;
    }
}

__global__ __launch_bounds__(256) void nca_step(
    const float* __restrict__ src, float* __restrict__ dst,
    const float* __restrict__ cf, const float* __restrict__ Kk,
    const float* __restrict__ w1, const float* __restrict__ b1,
    const float* __restrict__ w2, const float* __restrict__ b2,
    const float* __restrict__ w3, const float* __restrict__ b3) {
    __shared__ __align__(16) float s[SROWS * SSTR];

    const int tid = threadIdx.x;
    const int b   = blockIdx.z;
    const int gy0 = blockIdx.y * TH;
    const int gx0 = blockIdx.x * TW;
    const float* img = src + b * HH * WW;

    // ---- stage 42 rows x 21 float4-blocks, XOR-swizzled by (row>>1)&3 ----
    for (int t = tid; t < SROWS * NBLKX; t += 256) {
        int r = t / NBLKX, c = t - r * NBLKX;
        int gy = gy0 - 5 + r, gx = gx0 - 8 + c * 4;
        float4 v = make_float4(0.f, 0.f, 0.f, 0.f);
        if ((unsigned)gy < HH && (unsigned)gx < WW)
            v = *(const float4*)(img + gy * WW + gx);
        int pb = c ^ ((r >> 1) & 3);
        *(float4*)(s + r * SSTR + pb * 4) = v;
    }
    __syncthreads();

    const int tx = tid & 15, ty = tid >> 4;  // 16 x 16 threads
    const int rb = ty * 2;                   // 2 output rows per thread
    const int x0 = tx * 4;                   // 4 output px wide

    float acc[2][4];
#pragma unroll
    for (int r = 0; r < 2; ++r)
#pragma unroll
        for (int p = 0; p < 4; ++p) acc[r][p] = 0.f;

    // Window row W = staged row rb+W; output row r uses ky = W - r.
    // Output px x0+p reads staged words x0+p+3 .. x0+p+13 (stage origin gx0-8).
    // pass 1: ky 0..4  (W 0..5); pass 2: ky 5..10 (W 5..11)
    {
        float ka[55];
#pragma unroll
        for (int j = 0; j < 55; ++j) ka[j] = Kk[j];  // uniform -> batched s_load
#pragma unroll
        for (int W = 0; W < 6; ++W) {
            int SR = rb + W;
            int sw = (SR >> 1) & 3;
            const float* rowp = s + SR * SSTR;
            float win[20];
#pragma unroll
            for (int i = 0; i < 5; ++i)
                *(float4*)(win + 4 * i) = *(const float4*)(rowp + ((tx + i) ^ sw) * 4);
#pragma unroll
            for (int r = 0; r < 2; ++r) {
                const int ky = W - r;
                if (ky >= 0 && ky <= 4) {
#pragma unroll
                    for (int kx = 0; kx < 11; ++kx) {
                        float kv = ka[ky * 11 + kx];
#pragma unroll
                        for (int p = 0; p < 4; ++p)
                            acc[r][p] = fmaf(win[p + 3 + kx], kv, acc[r][p]);
                    }
                }
            }
        }
    }
    {
        float kb[66];
#pragma unroll
        for (int j = 0; j < 66; ++j) kb[j] = Kk[55 + j];
#pragma unroll
        for (int W = 5; W < 12; ++W) {
            int SR = rb + W;
            int sw = (SR >> 1) & 3;
            const float* rowp = s + SR * SSTR;
            float win[20];
#pragma unroll
            for (int i = 0; i < 5; ++i)
                *(float4*)(win + 4 * i) = *(const float4*)(rowp + ((tx + i) ^ sw) * 4);
#pragma unroll
            for (int r = 0; r < 2; ++r) {
                const int ky = W - r;
                if (ky >= 5 && ky <= 10) {
#pragma unroll
                    for (int kx = 0; kx < 11; ++kx) {
                        float kv = kb[(ky - 5) * 11 + kx];
#pragma unroll
                        for (int p = 0; p < 4; ++p)
                            acc[r][p] = fmaf(win[p + 3 + kx], kv, acc[r][p]);
                    }
                }
            }
        }
    }

    // ---- MLP + residual + clip + store (2 rows x float4) ----
    const float A = cf[0], B = cf[1];
    const bool fast = cf[2] > 0.5f;
    float* dimg = dst + b * HH * WW;
#pragma unroll
    for (int r = 0; r < 2; ++r) {
        int SRc = rb + r + 5;
        int sw = (SRc >> 1) & 3;
        const float4 xcv = *(const float4*)(s + SRc * SSTR + ((tx + 2) ^ sw) * 4);
        const float xc[4] = {xcv.x, xcv.y, xcv.z, xcv.w};
        float res[4];
        if (fast) {
#pragma unroll
            for (int p = 0; p < 4; ++p) {
                float v = acc[r][p];
                float y = (v >= 0.f) ? v * A : (-v) * B;  // R5 bug: was v*B
                res[p] = fminf(fmaxf(xc[p] + y, 0.f), 1.f);
            }
        } else {
#pragma unroll
            for (int p = 0; p < 4; ++p) {
                float y = mlp_full(acc[r][p], w1, b1, w2, b2, w3, b3);
                res[p] = fminf(fmaxf(xc[p] + y, 0.f), 1.f);
            }
        }
        *(float4*)(dimg + (gy0 + rb + r) * WW + gx0 + x0) =
            make_float4(res[0], res[1], res[2], res[3]);
    }
}

extern "C" void kernel_launch(void* const* d_in, const int* in_sizes, int n_in,
                              void* d_out, int out_size, void* d_ws, size_t ws_size,
                              hipStream_t stream) {
    const float* x  = (const float*)d_in[0];
    const float* Kk = (const float*)d_in[1];
    const float* w1 = (const float*)d_in[2];
    const float* b1 = (const float*)d_in[3];
    const float* w2 = (const float*)d_in[4];
    const float* b2 = (const float*)d_in[5];
    const float* w3 = (const float*)d_in[6];
    const float* b3 = (const float*)d_in[7];
    float* out = (float*)d_out;
    float* cf  = (float*)d_ws;  // [A, B, zero-flag] — rewritten every call

    nca_coef<<<1, 64, 0, stream>>>(w1, b1, w2, b2, w3, b3, cf);
    nca_copy_x<<<SLAB / (256 * 4), 256, 0, stream>>>(x, out);

    dim3 grid(WW / TW, HH / TH, BB);  // 4 x 8 x 16 = 512 blocks x 256 thr
    for (int k = 0; k < NSTEPS; ++k) {
        nca_step<<<grid, 256, 0, stream>>>(out + (size_t)k * SLAB,
                                           out + (size_t)(k + 1) * SLAB,
                                           cf, Kk, w1, b1, w2, b2, w3, b3);
    }
}